// Round 1
// baseline (494.511 us; speedup 1.0000x reference)
//
#include <hip/hip_runtime.h>
#include <math.h>

#define D_IN   4096
#define D_OUT  4096
#define M_ROWS 8192          // B*S = 4*2048
#define RANK   8
#define SCALING 2.0f
#define EPS_N  1e-8f

// ---------------------------------------------------------------------------
// Pass 1: mag_scale[o] = mag[o] / (||W_o + 2*B_o*A|| + eps)
//         Bm[o][r]     = 2 * B[o][r] * mag_scale[o]
// One W-row per wave, 4 waves/block -> 1024 blocks -> 4 blocks/CU,
// 16 waves/CU (2x the previous 8) for latency hiding. Loop has a
// compile-time trip count of 16 so the compiler can pipeline loads.
// ---------------------------------------------------------------------------
__global__ __launch_bounds__(256, 4) void k_magscale(
    const float* __restrict__ W,     // [D_OUT, D_IN]
    const float* __restrict__ A,     // [RANK, D_IN]
    const float* __restrict__ Bl,    // [D_OUT, RANK]
    const float* __restrict__ mag,   // [D_OUT]
    float* __restrict__ mag_scale,   // [D_OUT]
    float* __restrict__ Bm)          // [D_OUT, RANK]
{
    const int wave = threadIdx.x >> 6;
    const int lane = threadIdx.x & 63;
    const int o = blockIdx.x * 4 + wave;
    const float* W0 = W + (size_t)o * D_IN;

    float b0[RANK];
#pragma unroll
    for (int r = 0; r < RANK; ++r) b0[r] = Bl[o * RANK + r];

    float acc = 0.f;
#pragma unroll 2
    for (int k = 0; k < 16; ++k) {
        const int i = lane * 4 + k * 256;
        float4 w0 = *(const float4*)(W0 + i);
        float4 a4[RANK];
#pragma unroll
        for (int r = 0; r < RANK; ++r)
            a4[r] = *(const float4*)(A + r * D_IN + i);
        float dx = 0.f, dy = 0.f, dz = 0.f, dw = 0.f;
#pragma unroll
        for (int r = 0; r < RANK; ++r) {
            dx += b0[r] * a4[r].x; dy += b0[r] * a4[r].y;
            dz += b0[r] * a4[r].z; dw += b0[r] * a4[r].w;
        }
        float t;
        t = w0.x + SCALING * dx; acc += t * t;
        t = w0.y + SCALING * dy; acc += t * t;
        t = w0.z + SCALING * dz; acc += t * t;
        t = w0.w + SCALING * dw; acc += t * t;
    }
#pragma unroll
    for (int off = 32; off > 0; off >>= 1)
        acc += __shfl_down(acc, off, 64);
    if (lane == 0) {
        float ms0 = mag[o] / (sqrtf(acc) + EPS_N);
        mag_scale[o] = ms0;
        float4 lo, hi;
        lo.x = SCALING * b0[0] * ms0; lo.y = SCALING * b0[1] * ms0;
        lo.z = SCALING * b0[2] * ms0; lo.w = SCALING * b0[3] * ms0;
        hi.x = SCALING * b0[4] * ms0; hi.y = SCALING * b0[5] * ms0;
        hi.z = SCALING * b0[6] * ms0; hi.w = SCALING * b0[7] * ms0;
        *(float4*)(Bm + (size_t)o * RANK)     = lo;
        *(float4*)(Bm + (size_t)o * RANK + 4) = hi;
    }
}

// ---------------------------------------------------------------------------
// Fused pass 2+3. Block = 8 m-rows (4 waves x 2 rows) -> 1024 blocks ->
// 4 blocks/CU, 16 waves/CU. Phase A: lx[8][8] = x-tile . A^T in LDS.
// Phase B: per o-tile of 1024, batch-load all 8 base float4s into regs
// (8 KB/wave in flight by construction), then compute + store.
// ---------------------------------------------------------------------------
#define MT 8

__global__ __launch_bounds__(256, 4) void k_fused(
    const float* __restrict__ x,          // [M_ROWS, D_IN]
    const float* __restrict__ A,          // [RANK, D_IN]
    const float* __restrict__ base,       // [M_ROWS, D_OUT]
    const float* __restrict__ Bm,         // [D_OUT, RANK]
    const float* __restrict__ mag_scale,  // [D_OUT]
    float* __restrict__ out)              // [M_ROWS, D_OUT]
{
    const int wave = threadIdx.x >> 6;
    const int lane = threadIdx.x & 63;
    const int mb = blockIdx.x * MT;

    __shared__ float slx[MT][RANK];

    // ---------------- Phase A: rows mb + wave*2 + {0,1} --------------------
    const float* x0 = x + (size_t)(mb + wave * 2) * D_IN;
    float acc[2][RANK];
#pragma unroll
    for (int g = 0; g < 2; ++g)
#pragma unroll
        for (int r = 0; r < RANK; ++r) acc[g][r] = 0.f;

#pragma unroll 2
    for (int k = 0; k < 16; ++k) {
        const int i = lane * 4 + k * 256;
        float4 a4[RANK];
#pragma unroll
        for (int r = 0; r < RANK; ++r)
            a4[r] = *(const float4*)(A + r * D_IN + i);
        float4 xa = *(const float4*)(x0 + i);
        float4 xb = *(const float4*)(x0 + D_IN + i);
#pragma unroll
        for (int r = 0; r < RANK; ++r) {
            acc[0][r] += xa.x * a4[r].x + xa.y * a4[r].y +
                         xa.z * a4[r].z + xa.w * a4[r].w;
            acc[1][r] += xb.x * a4[r].x + xb.y * a4[r].y +
                         xb.z * a4[r].z + xb.w * a4[r].w;
        }
    }
#pragma unroll
    for (int g = 0; g < 2; ++g) {
#pragma unroll
        for (int r = 0; r < RANK; ++r) {
            float v = acc[g][r];
#pragma unroll
            for (int off = 32; off > 0; off >>= 1)
                v += __shfl_down(v, off, 64);
            if (lane == 0) slx[wave * 2 + g][r] = v;
        }
    }
    __syncthreads();

    // ---------------- Phase B: epilogue over full D_OUT --------------------
#pragma unroll
    for (int tile = 0; tile < 4; ++tile) {
        const int o = tile * 1024 + threadIdx.x * 4;
        const float4 ms4 = *(const float4*)(mag_scale + o);
        float bm[4][RANK];
#pragma unroll
        for (int j = 0; j < 4; ++j) {
            float4 lo = *(const float4*)(Bm + (size_t)(o + j) * RANK);
            float4 hi = *(const float4*)(Bm + (size_t)(o + j) * RANK + 4);
            bm[j][0] = lo.x; bm[j][1] = lo.y; bm[j][2] = lo.z; bm[j][3] = lo.w;
            bm[j][4] = hi.x; bm[j][5] = hi.y; bm[j][6] = hi.z; bm[j][7] = hi.w;
        }
        // batched base loads: 8 float4 in flight before any compute/store
        float4 b4[MT];
#pragma unroll
        for (int mi = 0; mi < MT; ++mi)
            b4[mi] = *(const float4*)(base + (size_t)(mb + mi) * D_OUT + o);
#pragma unroll
        for (int mi = 0; mi < MT; ++mi) {
            float4 llo = *(const float4*)&slx[mi][0];   // broadcast ds_read
            float4 lhi = *(const float4*)&slx[mi][4];
            float l[RANK] = { llo.x, llo.y, llo.z, llo.w,
                              lhi.x, lhi.y, lhi.z, lhi.w };
            float rx = b4[mi].x * ms4.x;
            float ry = b4[mi].y * ms4.y;
            float rz = b4[mi].z * ms4.z;
            float rw = b4[mi].w * ms4.w;
#pragma unroll
            for (int r = 0; r < RANK; ++r) {
                rx += l[r] * bm[0][r];
                ry += l[r] * bm[1][r];
                rz += l[r] * bm[2][r];
                rw += l[r] * bm[3][r];
            }
            *(float4*)(out + (size_t)(mb + mi) * D_OUT + o) =
                make_float4(rx, ry, rz, rw);
        }
    }
}

// ---------------------------------------------------------------------------
extern "C" void kernel_launch(void* const* d_in, const int* in_sizes, int n_in,
                              void* d_out, int out_size, void* d_ws, size_t ws_size,
                              hipStream_t stream) {
    const float* x        = (const float*)d_in[0];  // [4,2048,4096]
    const float* base_out = (const float*)d_in[1];  // [4,2048,4096]
    const float* base_w   = (const float*)d_in[2];  // [4096,4096]
    const float* lora_A   = (const float*)d_in[3];  // [8,4096]
    const float* lora_B   = (const float*)d_in[4];  // [4096,8]
    const float* mag      = (const float*)d_in[5];  // [4096]
    float* out = (float*)d_out;

    float* mag_scale = (float*)d_ws;                // 4096 f
    float* Bm        = mag_scale + D_OUT;           // 4096*8 f

    k_magscale<<<D_OUT / 4, 256, 0, stream>>>(base_w, lora_A, lora_B, mag,
                                              mag_scale, Bm);
    k_fused<<<M_ROWS / MT, 256, 0, stream>>>(x, lora_A, base_out, Bm,
                                             mag_scale, out);
}

// Round 2
// 408.565 us; speedup vs baseline: 1.2104x; 1.2104x over previous
//
#include <hip/hip_runtime.h>
#include <math.h>

#define D_IN   4096
#define D_OUT  4096
#define M_ROWS 8192          // B*S = 4*2048
#define RANK   8
#define SCALING 2.0f
#define EPS_N  1e-8f

// Non-temporal (no-allocate) access helpers: use-once streams must not
// thrash L2/L3. A, Bm, mag_scale, slx stay default-cached.
typedef float f4_t __attribute__((ext_vector_type(4)));

__device__ __forceinline__ f4_t ntl4(const float* p) {
    return __builtin_nontemporal_load((const f4_t*)p);
}
__device__ __forceinline__ void nts4(float* p, f4_t v) {
    __builtin_nontemporal_store(v, (f4_t*)p);
}

// ---------------------------------------------------------------------------
// Pass 1: mag_scale[o] = mag[o] / (||W_o + 2*B_o*A|| + eps)
//         Bm[o][r]     = 2 * B[o][r] * mag_scale[o]
// R0-proven geometry: G=2 rows/wave, 4 waves/block, 512 blocks.
// W is use-once -> non-temporal loads. A is hot (L2) -> cached loads.
// ---------------------------------------------------------------------------
__global__ __launch_bounds__(256, 2) void k_magscale(
    const float* __restrict__ W,     // [D_OUT, D_IN]
    const float* __restrict__ A,     // [RANK, D_IN]
    const float* __restrict__ Bl,    // [D_OUT, RANK]
    const float* __restrict__ mag,   // [D_OUT]
    float* __restrict__ mag_scale,   // [D_OUT]
    float* __restrict__ Bm)          // [D_OUT, RANK]
{
    const int wave = threadIdx.x >> 6;
    const int lane = threadIdx.x & 63;
    const int o0 = blockIdx.x * 8 + wave * 2;       // rows o0, o0+1
    const float* W0 = W + (size_t)o0 * D_IN;
    const float* W1 = W0 + D_IN;

    float b0[RANK], b1[RANK];
#pragma unroll
    for (int r = 0; r < RANK; ++r) {
        b0[r] = Bl[o0 * RANK + r];
        b1[r] = Bl[(o0 + 1) * RANK + r];
    }

    float acc0 = 0.f, acc1 = 0.f;
    for (int i = lane * 4; i < D_IN; i += 256) {
        float4 a4[RANK];
#pragma unroll
        for (int r = 0; r < RANK; ++r)
            a4[r] = *(const float4*)(A + r * D_IN + i);
        f4_t w0 = ntl4(W0 + i);
        f4_t w1 = ntl4(W1 + i);

        float d0x = 0.f, d0y = 0.f, d0z = 0.f, d0w = 0.f;
        float d1x = 0.f, d1y = 0.f, d1z = 0.f, d1w = 0.f;
#pragma unroll
        for (int r = 0; r < RANK; ++r) {
            d0x += b0[r] * a4[r].x; d0y += b0[r] * a4[r].y;
            d0z += b0[r] * a4[r].z; d0w += b0[r] * a4[r].w;
            d1x += b1[r] * a4[r].x; d1y += b1[r] * a4[r].y;
            d1z += b1[r] * a4[r].z; d1w += b1[r] * a4[r].w;
        }
        float t;
        t = w0.x + SCALING * d0x; acc0 += t * t;
        t = w0.y + SCALING * d0y; acc0 += t * t;
        t = w0.z + SCALING * d0z; acc0 += t * t;
        t = w0.w + SCALING * d0w; acc0 += t * t;
        t = w1.x + SCALING * d1x; acc1 += t * t;
        t = w1.y + SCALING * d1y; acc1 += t * t;
        t = w1.z + SCALING * d1z; acc1 += t * t;
        t = w1.w + SCALING * d1w; acc1 += t * t;
    }
#pragma unroll
    for (int off = 32; off > 0; off >>= 1) {
        acc0 += __shfl_down(acc0, off, 64);
        acc1 += __shfl_down(acc1, off, 64);
    }
    if (lane == 0) {
        float ms0 = mag[o0] / (sqrtf(acc0) + EPS_N);
        float ms1 = mag[o0 + 1] / (sqrtf(acc1) + EPS_N);
        mag_scale[o0] = ms0;
        mag_scale[o0 + 1] = ms1;
#pragma unroll
        for (int r = 0; r < RANK; ++r) {
            Bm[o0 * RANK + r]       = SCALING * b0[r] * ms0;
            Bm[(o0 + 1) * RANK + r] = SCALING * b1[r] * ms1;
        }
    }
}

// ---------------------------------------------------------------------------
// Fused pass 2+3 — byte-identical geometry to the R0 kernel (174 µs),
// with non-temporal x/base loads and out stores (the only change).
// Block = 16 m-rows (4 waves x G=4 rows), 512 blocks, 2 blocks/CU.
// ---------------------------------------------------------------------------
#define MT 16

__global__ __launch_bounds__(256, 2) void k_fused(
    const float* __restrict__ x,          // [M_ROWS, D_IN]
    const float* __restrict__ A,          // [RANK, D_IN]
    const float* __restrict__ base,       // [M_ROWS, D_OUT]
    const float* __restrict__ Bm,         // [D_OUT, RANK]
    const float* __restrict__ mag_scale,  // [D_OUT]
    float* __restrict__ out)              // [M_ROWS, D_OUT]
{
    const int wave = threadIdx.x >> 6;
    const int lane = threadIdx.x & 63;
    const int mb = blockIdx.x * MT;

    __shared__ float slx[MT][RANK];

    // ---------------- Phase A: lx for rows mb + wave*4 + {0..3} ------------
    const float* x0 = x + (size_t)(mb + wave * 4) * D_IN;
    float acc[4][RANK];
#pragma unroll
    for (int g = 0; g < 4; ++g)
#pragma unroll
        for (int r = 0; r < RANK; ++r) acc[g][r] = 0.f;

    for (int i = lane * 4; i < D_IN; i += 256) {
        float4 a4[RANK];
#pragma unroll
        for (int r = 0; r < RANK; ++r)
            a4[r] = *(const float4*)(A + r * D_IN + i);
#pragma unroll
        for (int g = 0; g < 4; ++g) {
            f4_t x4 = ntl4(x0 + (size_t)g * D_IN + i);
#pragma unroll
            for (int r = 0; r < RANK; ++r)
                acc[g][r] += x4.x * a4[r].x + x4.y * a4[r].y +
                             x4.z * a4[r].z + x4.w * a4[r].w;
        }
    }
#pragma unroll
    for (int g = 0; g < 4; ++g) {
#pragma unroll
        for (int r = 0; r < RANK; ++r) {
            float v = acc[g][r];
#pragma unroll
            for (int off = 32; off > 0; off >>= 1)
                v += __shfl_down(v, off, 64);
            if (lane == 0) slx[wave * 4 + g][r] = v;
        }
    }
    __syncthreads();

    // ---------------- Phase B: epilogue over full D_OUT --------------------
#pragma unroll
    for (int tile = 0; tile < 4; ++tile) {
        const int o = tile * 1024 + threadIdx.x * 4;
        const float4 ms4 = *(const float4*)(mag_scale + o);
        float bm[4][RANK];
#pragma unroll
        for (int j = 0; j < 4; ++j) {
            float4 lo = *(const float4*)(Bm + (size_t)(o + j) * RANK);
            float4 hi = *(const float4*)(Bm + (size_t)(o + j) * RANK + 4);
            bm[j][0] = lo.x; bm[j][1] = lo.y; bm[j][2] = lo.z; bm[j][3] = lo.w;
            bm[j][4] = hi.x; bm[j][5] = hi.y; bm[j][6] = hi.z; bm[j][7] = hi.w;
        }
        for (int mi = 0; mi < MT; ++mi) {
            const size_t row = (size_t)(mb + mi) * D_OUT + o;
            f4_t b4 = ntl4(base + row);
            float l[RANK];
#pragma unroll
            for (int r = 0; r < RANK; ++r) l[r] = slx[mi][r];

            float rx = b4.x * ms4.x;
            float ry = b4.y * ms4.y;
            float rz = b4.z * ms4.z;
            float rw = b4.w * ms4.w;
#pragma unroll
            for (int r = 0; r < RANK; ++r) {
                rx += l[r] * bm[0][r];
                ry += l[r] * bm[1][r];
                rz += l[r] * bm[2][r];
                rw += l[r] * bm[3][r];
            }
            f4_t res;
            res.x = rx; res.y = ry; res.z = rz; res.w = rw;
            nts4(out + row, res);
        }
    }
}

// ---------------------------------------------------------------------------
extern "C" void kernel_launch(void* const* d_in, const int* in_sizes, int n_in,
                              void* d_out, int out_size, void* d_ws, size_t ws_size,
                              hipStream_t stream) {
    const float* x        = (const float*)d_in[0];  // [4,2048,4096]
    const float* base_out = (const float*)d_in[1];  // [4,2048,4096]
    const float* base_w   = (const float*)d_in[2];  // [4096,4096]
    const float* lora_A   = (const float*)d_in[3];  // [8,4096]
    const float* lora_B   = (const float*)d_in[4];  // [4096,8]
    const float* mag      = (const float*)d_in[5];  // [4096]
    float* out = (float*)d_out;

    float* mag_scale = (float*)d_ws;                // 4096 f
    float* Bm        = mag_scale + D_OUT;           // 4096*8 f

    k_magscale<<<D_OUT / 8, 256, 0, stream>>>(base_w, lora_A, lora_B, mag,
                                              mag_scale, Bm);
    k_fused<<<M_ROWS / MT, 256, 0, stream>>>(x, lora_A, base_out, Bm,
                                             mag_scale, out);
}